// Round 1
// baseline (302.713 us; speedup 1.0000x reference)
//
#include <hip/hip_runtime.h>

// 8x8 block DCT: C = A * B * A^T for every non-overlapping 8x8 block.
// One thread per block. Memory-bound: 128 MiB in + 128 MiB out -> ~43 us floor.
// DCT matrix hard-coded (compile-time constants -> SGPR/immediate operands,
// no LDS broadcast traffic).

__global__ __launch_bounds__(256) void dct8x8_kernel(const float* __restrict__ x,
                                                     float* __restrict__ out,
                                                     int nblocks) {
    // A[i][n] = sqrt(2/8) * c_i * cos((2n+1) * i * pi / 16), c_0 = 1/sqrt(2)
    constexpr float A[8][8] = {
        { 0.35355339059327373f,  0.35355339059327373f,  0.35355339059327373f,  0.35355339059327373f,
          0.35355339059327373f,  0.35355339059327373f,  0.35355339059327373f,  0.35355339059327373f},
        { 0.49039264020161522f,  0.41573480615127262f,  0.27778511650980114f,  0.09754516100806417f,
         -0.09754516100806417f, -0.27778511650980114f, -0.41573480615127262f, -0.49039264020161522f},
        { 0.46193976625564337f,  0.19134171618254492f, -0.19134171618254492f, -0.46193976625564337f,
         -0.46193976625564337f, -0.19134171618254492f,  0.19134171618254492f,  0.46193976625564337f},
        { 0.41573480615127262f, -0.09754516100806417f, -0.49039264020161522f, -0.27778511650980114f,
          0.27778511650980114f,  0.49039264020161522f,  0.09754516100806417f, -0.41573480615127262f},
        { 0.35355339059327373f, -0.35355339059327373f, -0.35355339059327373f,  0.35355339059327373f,
          0.35355339059327373f, -0.35355339059327373f, -0.35355339059327373f,  0.35355339059327373f},
        { 0.27778511650980114f, -0.49039264020161522f,  0.09754516100806417f,  0.41573480615127262f,
         -0.41573480615127262f, -0.09754516100806417f,  0.49039264020161522f, -0.27778511650980114f},
        { 0.19134171618254492f, -0.46193976625564337f,  0.46193976625564337f, -0.19134171618254492f,
         -0.19134171618254492f,  0.46193976625564337f, -0.46193976625564337f,  0.19134171618254492f},
        { 0.09754516100806417f, -0.27778511650980114f,  0.41573480615127262f, -0.49039264020161522f,
          0.49039264020161522f, -0.41573480615127262f,  0.27778511650980114f, -0.09754516100806417f},
    };

    const int t = blockIdx.x * 256 + threadIdx.x;
    if (t >= nblocks) return;

    // t -> (image n, block-row bi, block-col bj); 128x128 blocks per 1024x1024 image
    const int n  = t >> 14;        // / 16384
    const int rm = t & 16383;
    const int bi = rm >> 7;        // / 128
    const int bj = rm & 127;

    const float* src = x + (((size_t)n << 20) + ((size_t)bi << 13) + ((size_t)bj << 3));

    // Load the 8x8 block. Two float4 loads per row; across a wave, consecutive
    // lanes are consecutive bj -> the pair of loads fully covers a contiguous
    // 2 KiB segment per image row (100% cache-line utilization).
    float r[8][8];
#pragma unroll
    for (int j = 0; j < 8; ++j) {
        const float4 lo = *reinterpret_cast<const float4*>(src + (size_t)j * 1024);
        const float4 hi = *reinterpret_cast<const float4*>(src + (size_t)j * 1024 + 4);
        r[j][0] = lo.x; r[j][1] = lo.y; r[j][2] = lo.z; r[j][3] = lo.w;
        r[j][4] = hi.x; r[j][5] = hi.y; r[j][6] = hi.z; r[j][7] = hi.w;
    }

    // Output block t occupies floats [t*64, t*64+64): thread-contiguous,
    // wave writes a contiguous 16 KiB region.
    float* dst = out + ((size_t)t << 6);

#pragma unroll
    for (int i = 0; i < 8; ++i) {
        // tmp = (A * B) row i : tmp[l] = sum_j A[i][j] * B[j][l]
        float tmp[8];
#pragma unroll
        for (int l = 0; l < 8; ++l) {
            float acc = A[i][0] * r[0][l];
#pragma unroll
            for (int j = 1; j < 8; ++j) acc = fmaf(A[i][j], r[j][l], acc);
            tmp[l] = acc;
        }
        // C row i : C[i][m] = sum_l tmp[l] * A[m][l]   (i.e. tmp @ A^T)
        float o[8];
#pragma unroll
        for (int m = 0; m < 8; ++m) {
            float acc = tmp[0] * A[m][0];
#pragma unroll
            for (int l = 1; l < 8; ++l) acc = fmaf(tmp[l], A[m][l], acc);
            o[m] = acc;
        }
        *reinterpret_cast<float4*>(dst + i * 8)     = make_float4(o[0], o[1], o[2], o[3]);
        *reinterpret_cast<float4*>(dst + i * 8 + 4) = make_float4(o[4], o[5], o[6], o[7]);
    }
}

extern "C" void kernel_launch(void* const* d_in, const int* in_sizes, int n_in,
                              void* d_out, int out_size, void* d_ws, size_t ws_size,
                              hipStream_t stream) {
    const float* x = (const float*)d_in[0];
    float* out = (float*)d_out;

    const int nblocks = out_size / 64;            // 524288 8x8 blocks
    const int grid = (nblocks + 255) / 256;       // 2048 workgroups of 256
    dct8x8_kernel<<<grid, 256, 0, stream>>>(x, out, nblocks);
}

// Round 2
// 237.233 us; speedup vs baseline: 1.2760x; 1.2760x over previous
//
#include <hip/hip_runtime.h>

// 8x8 block DCT: C = A * B * A^T per non-overlapping block.
// R2: stores staged through LDS (32 KiB, two 128-thread half-phases) so global
// writes are fully coalesced 4 KiB/instruction. R1 showed 2.2x write
// amplification (292 MB vs 131 MB) from 16 B/lane scattered stores.
// LDS float4 index XOR-swizzled (f4 ^ ((f4>>4)&15)) -> <=2-way bank conflicts
// on both the per-thread write and the coalesced read (2-way is free, m136).
// Compute order: M = B*A^T row-by-row during load (row j of M depends only on
// row j of B), then C = A*M row-by-row at staging time -> ~80 VGPR peak.

__global__ __launch_bounds__(256, 5) void dct8x8_kernel(const float* __restrict__ x,
                                                        float* __restrict__ out) {
    constexpr float A[8][8] = {
        { 0.35355339059327373f,  0.35355339059327373f,  0.35355339059327373f,  0.35355339059327373f,
          0.35355339059327373f,  0.35355339059327373f,  0.35355339059327373f,  0.35355339059327373f},
        { 0.49039264020161522f,  0.41573480615127262f,  0.27778511650980114f,  0.09754516100806417f,
         -0.09754516100806417f, -0.27778511650980114f, -0.41573480615127262f, -0.49039264020161522f},
        { 0.46193976625564337f,  0.19134171618254492f, -0.19134171618254492f, -0.46193976625564337f,
         -0.46193976625564337f, -0.19134171618254492f,  0.19134171618254492f,  0.46193976625564337f},
        { 0.41573480615127262f, -0.09754516100806417f, -0.49039264020161522f, -0.27778511650980114f,
          0.27778511650980114f,  0.49039264020161522f,  0.09754516100806417f, -0.41573480615127262f},
        { 0.35355339059327373f, -0.35355339059327373f, -0.35355339059327373f,  0.35355339059327373f,
          0.35355339059327373f, -0.35355339059327373f, -0.35355339059327373f,  0.35355339059327373f},
        { 0.27778511650980114f, -0.49039264020161522f,  0.09754516100806417f,  0.41573480615127262f,
         -0.41573480615127262f, -0.09754516100806417f,  0.49039264020161522f, -0.27778511650980114f},
        { 0.19134171618254492f, -0.46193976625564337f,  0.46193976625564337f, -0.19134171618254492f,
         -0.19134171618254492f,  0.46193976625564337f, -0.46193976625564337f,  0.19134171618254492f},
        { 0.09754516100806417f, -0.27778511650980114f,  0.41573480615127262f, -0.49039264020161522f,
          0.49039264020161522f, -0.41573480615127262f,  0.27778511650980114f, -0.09754516100806417f},
    };

    __shared__ float4 lds4[2048];  // 32 KiB staging buffer (one half-phase)

    const int tl = threadIdx.x;
    const int t  = blockIdx.x * 256 + tl;

    // t -> (image n, block-row bi, block-col bj); 128x128 blocks per image
    const int n  = t >> 14;
    const int rm = t & 16383;
    const int bi = rm >> 7;
    const int bj = rm & 127;

    const float* src = x + (((size_t)n << 20) + ((size_t)bi << 13) + ((size_t)bj << 3));

    // Load row j, immediately fold into M = B * A^T (row j of M needs only
    // row j of B): M[j][m] = sum_l B[j][l] * A[m][l]
    float M[8][8];
#pragma unroll
    for (int j = 0; j < 8; ++j) {
        const float4 lo = *reinterpret_cast<const float4*>(src + (size_t)j * 1024);
        const float4 hi = *reinterpret_cast<const float4*>(src + (size_t)j * 1024 + 4);
        const float b[8] = {lo.x, lo.y, lo.z, lo.w, hi.x, hi.y, hi.z, hi.w};
#pragma unroll
        for (int m = 0; m < 8; ++m) {
            float acc = b[0] * A[m][0];
#pragma unroll
            for (int l = 1; l < 8; ++l) acc = fmaf(b[l], A[m][l], acc);
            M[j][m] = acc;
        }
    }

    // Workgroup w owns blocks [w*256, w*256+256) -> output floats [w*16384, ...).
    float* outw = out + ((size_t)blockIdx.x << 14);

    const int half = tl >> 7;   // wave-uniform: waves 0,1 -> half 0; waves 2,3 -> half 1
    const int tr   = tl & 127;  // rank within half

#pragma unroll
    for (int h = 0; h < 2; ++h) {
        if (half == h) {
            // C = A * M, row by row, straight into swizzled LDS.
#pragma unroll
            for (int i = 0; i < 8; ++i) {
                float c[8];
#pragma unroll
                for (int m = 0; m < 8; ++m) {
                    float acc = A[i][0] * M[0][m];
#pragma unroll
                    for (int j = 1; j < 8; ++j) acc = fmaf(A[i][j], M[j][m], acc);
                    c[m] = acc;
                }
                const int f0 = tr * 16 + i * 2;       // logical float4 index
                const int f1 = f0 + 1;
                lds4[f0 ^ (tr & 15)] = make_float4(c[0], c[1], c[2], c[3]);
                lds4[f1 ^ (tr & 15)] = make_float4(c[4], c[5], c[6], c[7]);
            }
        }
        __syncthreads();
        // Cooperative coalesced store: 2048 float4 = 32 KiB contiguous,
        // 256 threads x 16 B = 4 KiB per iteration.
        float4* dst4 = reinterpret_cast<float4*>(outw + h * 8192);
#pragma unroll
        for (int s = 0; s < 8; ++s) {
            const int f4 = s * 256 + tl;
            dst4[f4] = lds4[f4 ^ ((f4 >> 4) & 15)];
        }
        __syncthreads();  // protect LDS reuse by the next half-phase
    }
}

extern "C" void kernel_launch(void* const* d_in, const int* in_sizes, int n_in,
                              void* d_out, int out_size, void* d_ws, size_t ws_size,
                              hipStream_t stream) {
    const float* x = (const float*)d_in[0];
    float* out = (float*)d_out;

    const int nblocks = out_size / 64;        // 524288
    const int grid = nblocks / 256;           // 2048 workgroups, exact
    dct8x8_kernel<<<grid, 256, 0, stream>>>(x, out);
}